// Round 6
// baseline (77.756 us; speedup 1.0000x reference)
//
#include <hip/hip_runtime.h>

#define S_LEN 4096
#define E_DIM 64
#define MODES 64
#define BH    128
#define NCH   4
#define CH    1024      // S_LEN / NCH
#define BK    64        // K-step (s) per round in k_fwd

typedef __attribute__((ext_vector_type(8))) short bf16x8;   // 8 bf16 in 4 VGPRs
typedef __attribute__((ext_vector_type(4))) float f32x4;

__device__ inline unsigned short f2bf(float f) {            // RTNE fp32->bf16
    unsigned int u = __float_as_uint(f);
    unsigned int r = u + 0x7FFFu + ((u >> 16) & 1u);
    return (unsigned short)(r >> 16);
}

// pack-position permutation (B-operand of both MFMA kernels): channel c ->
// position (c&3)*16 + (c>>2), so MFMA lane lr in n-tile nt owns channel
// 4*lr+nt, making the epilogue float4-contiguous per lane.
__device__ inline int posP(int c) { return ((c & 3) << 4) | (c >> 2); }

// ---------------------------------------------------------------------------
// Fused table build (one launch).  Twiddle tables in MFMA-FRAGMENT order
// (16-row x 32-col bf16 tiles, lane-major), so every A-operand load in
// k_fwd/k_inv is a single coalesced 1KB wave load instead of a 16-row gather.
// NEW (R6): __sincosf (HW approx) — angles in [0,2pi), err ~1e-6 << bf16 ulp.
//  blocks [1024,2048): weight prepack Wp[i] = bf16(wr)|bf16(wi)<<16
// ---------------------------------------------------------------------------
__global__ __launch_bounds__(256) void k_twp(const int* __restrict__ idx,
                                             const float* __restrict__ wr,
                                             const float* __restrict__ wi,
                                             unsigned short* __restrict__ Tf,
                                             unsigned short* __restrict__ Ui,
                                             unsigned int* __restrict__ Wp) {
    if (blockIdx.x < 1024) {
        int id = blockIdx.x * 256 + threadIdx.x;   // 64*4096
        int j = id >> 12;                          // mode row 0..63
        int s = id & (S_LEN - 1);
        int m = (idx[j] * s) & (S_LEN - 1);
        float ang = (float)m * (6.283185307179586476925287f / (float)S_LEN);
        float sv, cv;
        __sincosf(ang, &sv, &cv);
        // Tf fragment layout: mrow=j -> cos, mrow=64+j -> -sin
        const int tb = (s >> 5) * 4096 + ((s >> 3) & 3) * 128 + (s & 7);
        Tf[tb + ((j >> 4) * 64 + (j & 15)) * 8]              = f2bf(cv);
        Tf[tb + ((4 + (j >> 4)) * 64 + (j & 15)) * 8]        = f2bf(-sv);
        // Ui fragment layout: q=j -> cos, q=64+j -> +sin
        const int ub = (s >> 4) * 2048 + (s & 15) * 8;
        const int qc = ((j >> 3) & 3) * 128 + (j & 7);
        Ui[ub + (j >> 5) * 512 + qc]                          = f2bf(cv);
        Ui[ub + (2 + (j >> 5)) * 512 + qc]                    = f2bf(sv);
    } else {
        const int i = (blockIdx.x - 1024) * 256 + threadIdx.x;   // 262144
        Wp[i] = (unsigned int)f2bf(wr[i]) | ((unsigned int)f2bf(wi[i]) << 16);
    }
}

// ---------------------------------------------------------------------------
// K1 (MFMA): partial C[128m][64e] = T[128 x 1024chunk] * x[1024 x 64] per bh.
// grid = 128 bh x 4 chunks = 512 blocks (2/CU), 512 threads (8 waves).
// R4 structure (RESTORED after R5 dual-bank was neutral — k_fwd is at its BW
// floor): double-buffered Xs, one barrier per K-step; iter ks packs data for
// ks+1 and issues NT loads for ks+2.
// ---------------------------------------------------------------------------
__global__ __launch_bounds__(512) void k_fwd(const float* __restrict__ x,
                                             const unsigned short* __restrict__ Tf,
                                             float* __restrict__ xfp) {
    __shared__ unsigned short Xs[2][8 * 64 * 8];   // 2 x 8 KB, packs [kp][pos][8k]
    const int bh = blockIdx.x >> 2;
    const int c  = blockIdx.x & 3;
    const int t  = threadIdx.x;
    const int w  = t >> 6;          // wave 0..7
    const int l  = t & 63;
    const int lr = l & 15;
    const int lg = l >> 4;
    const int NIT = CH / BK;        // 16

    f32x4 acc[4];
    #pragma unroll
    for (int i = 0; i < 4; ++i) { acc[i][0]=0.f; acc[i][1]=0.f; acc[i][2]=0.f; acc[i][3]=0.f; }

    const float* xb = x + ((size_t)bh * S_LEN + c * CH) * E_DIM;
    // fragment-order A base: tile (st = c*32 + ks*2 + ksub, w), lane l
    const unsigned short* Tw = Tf + (size_t)(c * 32) * 4096 + w * 512 + l * 8;
    const int pkoff = (w * 64 + posP(l)) * 8;

    float xe[8];
    {   // iter-0 data, pack into Xs[0]
        const float* xg = xb + (size_t)(w * 8) * E_DIM + l;
        #pragma unroll
        for (int j = 0; j < 8; ++j) xe[j] = __builtin_nontemporal_load(xg + (size_t)j * E_DIM);
        union { unsigned short u[8]; bf16x8 v; } pk;
        #pragma unroll
        for (int j = 0; j < 8; ++j) pk.u[j] = f2bf(xe[j]);
        *(bf16x8*)&Xs[0][pkoff] = pk.v;
    }
    {   // issue loads for iter 1
        const float* xg = xb + (size_t)(BK + w * 8) * E_DIM + l;
        #pragma unroll
        for (int j = 0; j < 8; ++j) xe[j] = __builtin_nontemporal_load(xg + (size_t)j * E_DIM);
    }
    __syncthreads();

    #pragma unroll 2
    for (int ks = 0; ks < NIT; ++ks) {
        const int p = ks & 1;
        if (ks + 1 < NIT) {
            // pack xe (data for iter ks+1) into the other buffer
            union { unsigned short u[8]; bf16x8 v; } pk;
            #pragma unroll
            for (int j = 0; j < 8; ++j) pk.u[j] = f2bf(xe[j]);
            *(bf16x8*)&Xs[p ^ 1][pkoff] = pk.v;
            if (ks + 2 < NIT) {
                const float* xg = xb + (size_t)((ks + 2) * BK + w * 8) * E_DIM + l;
                #pragma unroll
                for (int j = 0; j < 8; ++j) xe[j] = __builtin_nontemporal_load(xg + (size_t)j * E_DIM);
            }
        }
        #pragma unroll
        for (int ksub = 0; ksub < 2; ++ksub) {
            const bf16x8 af = *(const bf16x8*)&Tw[(size_t)(ks * 2 + ksub) * 4096];
            #pragma unroll
            for (int nt = 0; nt < 4; ++nt) {
                const bf16x8 bfr = *(const bf16x8*)&Xs[p][((ksub * 4 + lg) * 64 + nt * 16 + lr) * 8];
                acc[nt] = __builtin_amdgcn_mfma_f32_16x16x32_bf16(af, bfr, acc[nt], 0, 0, 0);
            }
        }
        __syncthreads();
    }
    // posP-permuted packs: lane lr's tile nt holds e = 4*lr + nt -> f32x4 rows
    float* ob = xfp + ((size_t)c * BH + bh) * 8192;
    #pragma unroll
    for (int r = 0; r < 4; ++r) {
        f32x4 v;
        v[0] = acc[0][r]; v[1] = acc[1][r];
        v[2] = acc[2][r]; v[3] = acc[3][r];
        *(f32x4*)&ob[(size_t)(16 * w + lg * 4 + r) * 64 + 4 * lr] = v;
    }
}

// ---------------------------------------------------------------------------
// M (fp32 accum, bf16 packed weights): fused 4-plane chunk reduction + apply
// complex weights, scale, fold signs; write bf16 B-packs Qpk[bh][kp][pos][8k].
// NEW (R6): 512 blocks x 512 threads, block = 1 bh x 16 o, 32 KB LDS ->
// 2 blocks/CU co-resident, 4 waves/SIMD (was 2) for L2-latency hiding.
// Blocks sharing a bh are g, g+128, g+256, g+384 == same XCD (mod 8).
// ---------------------------------------------------------------------------
__global__ __launch_bounds__(512) void k_mix(const float* __restrict__ xfp,
                                             const unsigned int* __restrict__ Wp,
                                             const int* __restrict__ idx,
                                             unsigned short* __restrict__ Qpk) {
    __shared__ float xf[64 * 128];       // [e][m^swz], 32 KB
    const int g   = blockIdx.x;          // bh + ob4*128
    const int bh  = g & 127;
    const int ob4 = g >> 7;              // 16-o group 0..3
    const int t   = threadIdx.x;
    const size_t P = (size_t)BH * 8192;  // chunk plane stride
    const float* x0 = xfp + (size_t)bh * 8192;
    #pragma unroll
    for (int i = 0; i < 4; ++i) {
        const int off = i * 2048 + t * 4;
        const int mm  = off >> 6;
        const int e4  = off & 63;
        float4 v0 = *(const float4*)(x0 + off);
        float4 v1 = *(const float4*)(x0 + P + off);
        float4 v2 = *(const float4*)(x0 + 2 * P + off);
        float4 v3 = *(const float4*)(x0 + 3 * P + off);
        float4 v;
        v.x = (v0.x + v1.x) + (v2.x + v3.x);
        v.y = (v0.y + v1.y) + (v2.y + v3.y);
        v.z = (v0.z + v1.z) + (v2.z + v3.z);
        v.w = (v0.w + v1.w) + (v2.w + v3.w);
        xf[(e4 + 0) * 128 + (mm ^ (((e4 + 0) >> 2) & 31))] = v.x;
        xf[(e4 + 1) * 128 + (mm ^ (((e4 + 1) >> 2) & 31))] = v.y;
        xf[(e4 + 2) * 128 + (mm ^ (((e4 + 2) >> 2) & 31))] = v.z;
        xf[(e4 + 3) * 128 + (mm ^ (((e4 + 3) >> 2) & 31))] = v.w;
    }
    __syncthreads();
    const int k    = t & 63;
    const int osub = t >> 6;             // 0..7
    const int o0   = ob4 * 16 + osub * 2;
    float pr0 = 0.f, pi0 = 0.f, pr1 = 0.f, pi1 = 0.f;
    const unsigned int* wp = Wp + (size_t)o0 * 64 + k;
    #pragma unroll 4
    for (int e = 0; e < E_DIM; ++e) {
        const unsigned int w0 = wp[e * 4096];
        const unsigned int w1 = wp[e * 4096 + 64];
        const float a0 = __uint_as_float(w0 << 16);
        const float b0 = __uint_as_float(w0 & 0xFFFF0000u);
        const float a1 = __uint_as_float(w1 << 16);
        const float b1 = __uint_as_float(w1 & 0xFFFF0000u);
        const int swz = (e >> 2) & 31;
        const float Xr = xf[e * 128 + (k ^ swz)];
        const float Xi = xf[e * 128 + 64 + (k ^ swz)];
        pr0 = fmaf(Xr, a0, fmaf(-Xi, b0, pr0));
        pi0 = fmaf(Xr, b0, fmaf( Xi, a0, pi0));
        pr1 = fmaf(Xr, a1, fmaf(-Xi, b1, pr1));
        pi1 = fmaf(Xr, b1, fmaf( Xi, a1, pi1));
    }
    const float sc = (idx[k] == 0 ? 1.0f : 2.0f) / (float)S_LEN;
    unsigned short* qb = Qpk + (size_t)bh * 8192;
    const int kp = k >> 3, kl = k & 7;
    const int P0 = posP(o0), P1 = posP(o0 + 1);
    qb[(kp * 64 + P0) * 8 + kl]       = f2bf(sc * pr0);
    qb[(kp * 64 + P1) * 8 + kl]       = f2bf(sc * pr1);
    qb[((8 + kp) * 64 + P0) * 8 + kl] = f2bf(-sc * pi0);
    qb[((8 + kp) * 64 + P1) * 8 + kl] = f2bf(-sc * pi1);
}

// ---------------------------------------------------------------------------
// K2 (MFMA, LDS-free): out[128s x 64e] = U[128 x 128] * Q[128 x 64].
// grid = 128 bh x 32 s-chunks, 256 threads.  float4 NT stores.
// Ui in fragment order -> A loads are coalesced 1KB wave loads.  UNCHANGED.
// ---------------------------------------------------------------------------
__global__ __launch_bounds__(256) void k_inv(const unsigned short* __restrict__ Qpk,
                                             const unsigned short* __restrict__ Ui,
                                             float* __restrict__ out) {
    const int g  = blockIdx.x;                       // (bh%8) + sc*8 + (bh/8)*256
    const int bh = (g & 7) | ((g >> 8) << 3);
    const int sc = (g >> 3) & 31;
    const int t  = threadIdx.x;
    const int w  = t >> 6;
    const int l  = t & 63;
    const int lr = l & 15;
    const int lg = l >> 4;

    const unsigned short* qb = Qpk + (size_t)bh * 8192;
    // fragment-order A base: s-tiles su0 = sc*8 + w*2 (+1 for upper 16 rows)
    const unsigned short* U0 = Ui + (size_t)(sc * 8 + w * 2) * 2048 + l * 8;

    f32x4 acc[2][4];
    #pragma unroll
    for (int a = 0; a < 2; ++a)
        #pragma unroll
        for (int b = 0; b < 4; ++b) { acc[a][b][0]=0.f; acc[a][b][1]=0.f; acc[a][b][2]=0.f; acc[a][b][3]=0.f; }

    #pragma unroll
    for (int ksb = 0; ksb < 4; ++ksb) {
        const bf16x8 af0 = *(const bf16x8*)&U0[ksb * 512];
        const bf16x8 af1 = *(const bf16x8*)&U0[2048 + ksb * 512];
        #pragma unroll
        for (int nt = 0; nt < 4; ++nt) {
            const bf16x8 bfr = *(const bf16x8*)&qb[((ksb * 4 + lg) * 64 + nt * 16 + lr) * 8];
            acc[0][nt] = __builtin_amdgcn_mfma_f32_16x16x32_bf16(af0, bfr, acc[0][nt], 0, 0, 0);
            acc[1][nt] = __builtin_amdgcn_mfma_f32_16x16x32_bf16(af1, bfr, acc[1][nt], 0, 0, 0);
        }
    }
    float* ob = out + ((size_t)bh * S_LEN + sc * 128) * E_DIM;
    #pragma unroll
    for (int mt = 0; mt < 2; ++mt)
        #pragma unroll
        for (int r = 0; r < 4; ++r) {
            f32x4 v;
            v[0] = acc[mt][0][r]; v[1] = acc[mt][1][r];
            v[2] = acc[mt][2][r]; v[3] = acc[mt][3][r];
            __builtin_nontemporal_store(v,
                (f32x4*)&ob[(size_t)(w * 32 + mt * 16 + lg * 4 + r) * E_DIM + 4 * lr]);
        }
}

// ---------------------------------------------------------------------------
extern "C" void kernel_launch(void* const* d_in, const int* in_sizes, int n_in,
                              void* d_out, int out_size, void* d_ws, size_t ws_size,
                              hipStream_t stream) {
    const float* x  = (const float*)d_in[0];
    const float* wr = (const float*)d_in[1];
    const float* wi = (const float*)d_in[2];
    const int*  idx = (const int*)d_in[3];
    float* outp = (float*)d_out;
    char*  ws   = (char*)d_ws;

    // workspace (bytes): Tf 1MB | Ui 1MB | xfp 16MB | Qpk 2MB | Wp 1MB
    unsigned short* Tf  = (unsigned short*)(ws);
    unsigned short* Ui  = (unsigned short*)(ws + (1u << 20));
    float*          xfp = (float*)(ws + (2u << 20));
    unsigned short* Qpk = (unsigned short*)(ws + (18u << 20));
    unsigned int*   Wp  = (unsigned int*)(ws + (20u << 20));

    hipLaunchKernelGGL(k_twp, dim3(2048), dim3(256), 0, stream,
                       idx, wr, wi, Tf, Ui, Wp);
    hipLaunchKernelGGL(k_fwd, dim3(BH * NCH), dim3(512), 0, stream,
                       x, Tf, xfp);
    hipLaunchKernelGGL(k_mix, dim3(512), dim3(512), 0, stream,
                       xfp, Wp, idx, Qpk);
    hipLaunchKernelGGL(k_inv, dim3(BH * 32), dim3(256), 0, stream,
                       Qpk, Ui, outp);
}

// Round 7
// 71.755 us; speedup vs baseline: 1.0836x; 1.0836x over previous
//
#include <hip/hip_runtime.h>

#define S_LEN 4096
#define E_DIM 64
#define MODES 64
#define BH    128
#define NCH   4
#define CH    1024      // S_LEN / NCH
#define BK    64        // K-step (s) per round in k_fwd

typedef __attribute__((ext_vector_type(8))) short bf16x8;   // 8 bf16 in 4 VGPRs
typedef __attribute__((ext_vector_type(4))) float f32x4;
typedef __attribute__((ext_vector_type(4))) _Float16 f16x4;

__device__ inline unsigned short f2bf(float f) {            // RTNE fp32->bf16
    unsigned int u = __float_as_uint(f);
    unsigned int r = u + 0x7FFFu + ((u >> 16) & 1u);
    return (unsigned short)(r >> 16);
}

// pack-position permutation (B-operand of both MFMA kernels): channel c ->
// position (c&3)*16 + (c>>2), so MFMA lane lr in n-tile nt owns channel
// 4*lr+nt, making the epilogue float4-contiguous per lane.
__device__ inline int posP(int c) { return ((c & 3) << 4) | (c >> 2); }

// ---------------------------------------------------------------------------
// Fused table build (one launch).  Twiddle tables in MFMA-FRAGMENT order
// (16-row x 32-col bf16 tiles, lane-major), so every A-operand load in
// k_fwd/k_inv is a single coalesced 1KB wave load instead of a 16-row gather.
// __sincosf (R6, proven bf16-bit-identical) — angles in [0,2pi).
//  blocks [1024,2048): weight prepack Wp[i] = bf16(wr)|bf16(wi)<<16
// ---------------------------------------------------------------------------
__global__ __launch_bounds__(256) void k_twp(const int* __restrict__ idx,
                                             const float* __restrict__ wr,
                                             const float* __restrict__ wi,
                                             unsigned short* __restrict__ Tf,
                                             unsigned short* __restrict__ Ui,
                                             unsigned int* __restrict__ Wp) {
    if (blockIdx.x < 1024) {
        int id = blockIdx.x * 256 + threadIdx.x;   // 64*4096
        int j = id >> 12;                          // mode row 0..63
        int s = id & (S_LEN - 1);
        int m = (idx[j] * s) & (S_LEN - 1);
        float ang = (float)m * (6.283185307179586476925287f / (float)S_LEN);
        float sv, cv;
        __sincosf(ang, &sv, &cv);
        // Tf fragment layout: mrow=j -> cos, mrow=64+j -> -sin
        const int tb = (s >> 5) * 4096 + ((s >> 3) & 3) * 128 + (s & 7);
        Tf[tb + ((j >> 4) * 64 + (j & 15)) * 8]              = f2bf(cv);
        Tf[tb + ((4 + (j >> 4)) * 64 + (j & 15)) * 8]        = f2bf(-sv);
        // Ui fragment layout: q=j -> cos, q=64+j -> +sin
        const int ub = (s >> 4) * 2048 + (s & 15) * 8;
        const int qc = ((j >> 3) & 3) * 128 + (j & 7);
        Ui[ub + (j >> 5) * 512 + qc]                          = f2bf(cv);
        Ui[ub + (2 + (j >> 5)) * 512 + qc]                    = f2bf(sv);
    } else {
        const int i = (blockIdx.x - 1024) * 256 + threadIdx.x;   // 262144
        Wp[i] = (unsigned int)f2bf(wr[i]) | ((unsigned int)f2bf(wi[i]) << 16);
    }
}

// ---------------------------------------------------------------------------
// K1 (MFMA): partial C[128m][64e] = T[128 x 1024chunk] * x[1024 x 64] per bh.
// grid = 128 bh x 4 chunks = 512 blocks (2/CU), 512 threads (8 waves).
// R4 structure (proven): double-buffered Xs, one barrier per K-step; iter ks
// packs data for ks+1 and issues NT loads for ks+2.
// NEW (R7): epilogue stores partials as fp16 (halves xfp round-trip bytes;
// rel err 2^-11 << bf16 rounding already applied at MFMA inputs).
// ---------------------------------------------------------------------------
__global__ __launch_bounds__(512) void k_fwd(const float* __restrict__ x,
                                             const unsigned short* __restrict__ Tf,
                                             _Float16* __restrict__ xfp) {
    __shared__ unsigned short Xs[2][8 * 64 * 8];   // 2 x 8 KB, packs [kp][pos][8k]
    const int bh = blockIdx.x >> 2;
    const int c  = blockIdx.x & 3;
    const int t  = threadIdx.x;
    const int w  = t >> 6;          // wave 0..7
    const int l  = t & 63;
    const int lr = l & 15;
    const int lg = l >> 4;
    const int NIT = CH / BK;        // 16

    f32x4 acc[4];
    #pragma unroll
    for (int i = 0; i < 4; ++i) { acc[i][0]=0.f; acc[i][1]=0.f; acc[i][2]=0.f; acc[i][3]=0.f; }

    const float* xb = x + ((size_t)bh * S_LEN + c * CH) * E_DIM;
    // fragment-order A base: tile (st = c*32 + ks*2 + ksub, w), lane l
    const unsigned short* Tw = Tf + (size_t)(c * 32) * 4096 + w * 512 + l * 8;
    const int pkoff = (w * 64 + posP(l)) * 8;

    float xe[8];
    {   // iter-0 data, pack into Xs[0]
        const float* xg = xb + (size_t)(w * 8) * E_DIM + l;
        #pragma unroll
        for (int j = 0; j < 8; ++j) xe[j] = __builtin_nontemporal_load(xg + (size_t)j * E_DIM);
        union { unsigned short u[8]; bf16x8 v; } pk;
        #pragma unroll
        for (int j = 0; j < 8; ++j) pk.u[j] = f2bf(xe[j]);
        *(bf16x8*)&Xs[0][pkoff] = pk.v;
    }
    {   // issue loads for iter 1
        const float* xg = xb + (size_t)(BK + w * 8) * E_DIM + l;
        #pragma unroll
        for (int j = 0; j < 8; ++j) xe[j] = __builtin_nontemporal_load(xg + (size_t)j * E_DIM);
    }
    __syncthreads();

    #pragma unroll 2
    for (int ks = 0; ks < NIT; ++ks) {
        const int p = ks & 1;
        if (ks + 1 < NIT) {
            // pack xe (data for iter ks+1) into the other buffer
            union { unsigned short u[8]; bf16x8 v; } pk;
            #pragma unroll
            for (int j = 0; j < 8; ++j) pk.u[j] = f2bf(xe[j]);
            *(bf16x8*)&Xs[p ^ 1][pkoff] = pk.v;
            if (ks + 2 < NIT) {
                const float* xg = xb + (size_t)((ks + 2) * BK + w * 8) * E_DIM + l;
                #pragma unroll
                for (int j = 0; j < 8; ++j) xe[j] = __builtin_nontemporal_load(xg + (size_t)j * E_DIM);
            }
        }
        #pragma unroll
        for (int ksub = 0; ksub < 2; ++ksub) {
            const bf16x8 af = *(const bf16x8*)&Tw[(size_t)(ks * 2 + ksub) * 4096];
            #pragma unroll
            for (int nt = 0; nt < 4; ++nt) {
                const bf16x8 bfr = *(const bf16x8*)&Xs[p][((ksub * 4 + lg) * 64 + nt * 16 + lr) * 8];
                acc[nt] = __builtin_amdgcn_mfma_f32_16x16x32_bf16(af, bfr, acc[nt], 0, 0, 0);
            }
        }
        __syncthreads();
    }
    // posP-permuted packs: lane lr's tile nt holds e = 4*lr + nt -> f16x4 rows
    _Float16* ob = xfp + ((size_t)c * BH + bh) * 8192;
    #pragma unroll
    for (int r = 0; r < 4; ++r) {
        f16x4 v;
        v[0] = (_Float16)acc[0][r]; v[1] = (_Float16)acc[1][r];
        v[2] = (_Float16)acc[2][r]; v[3] = (_Float16)acc[3][r];
        *(f16x4*)&ob[(size_t)(16 * w + lg * 4 + r) * 64 + 4 * lr] = v;
    }
}

// ---------------------------------------------------------------------------
// M (fp32 accum, bf16 packed weights): fused 4-plane chunk reduction + apply
// complex weights, scale, fold signs; write bf16 B-packs Qpk[bh][kp][pos][8k].
// R3-PROVEN shape restored (R6's 1bh split regressed: Wp amortization halved).
// 256 blocks x 512 threads, block = 2 bh x 16 o, both bh planes in 64KB fp32
// LDS (transposed [e][m] + XOR swizzle).  NEW (R7): xfp reads are fp16.
// Blocks sharing a bh pair are g, g+64, g+128, g+192 == same XCD (mod 8).
// ---------------------------------------------------------------------------
__global__ __launch_bounds__(512) void k_mix(const _Float16* __restrict__ xfp,
                                             const unsigned int* __restrict__ Wp,
                                             const int* __restrict__ idx,
                                             unsigned short* __restrict__ Qpk) {
    __shared__ float xf[2 * 64 * 128];   // [b][e][m^swz], 64 KB
    const int g   = blockIdx.x;
    const int bhp = g & 63;              // bh pair: 2*bhp, 2*bhp+1
    const int ob4 = g >> 6;              // 16-o group 0..3
    const int t   = threadIdx.x;
    const size_t P = (size_t)BH * 8192;  // chunk plane stride (halves)
    #pragma unroll
    for (int b = 0; b < 2; ++b) {
        const _Float16* x0 = xfp + (size_t)(2 * bhp + b) * 8192;
        float* xl = xf + b * 8192;
        #pragma unroll
        for (int i = 0; i < 4; ++i) {
            const int off = i * 2048 + t * 4;
            const int mm  = off >> 6;
            const int e4  = off & 63;
            f16x4 v0 = *(const f16x4*)(x0 + off);
            f16x4 v1 = *(const f16x4*)(x0 + P + off);
            f16x4 v2 = *(const f16x4*)(x0 + 2 * P + off);
            f16x4 v3 = *(const f16x4*)(x0 + 3 * P + off);
            float4 v;
            v.x = ((float)v0[0] + (float)v1[0]) + ((float)v2[0] + (float)v3[0]);
            v.y = ((float)v0[1] + (float)v1[1]) + ((float)v2[1] + (float)v3[1]);
            v.z = ((float)v0[2] + (float)v1[2]) + ((float)v2[2] + (float)v3[2]);
            v.w = ((float)v0[3] + (float)v1[3]) + ((float)v2[3] + (float)v3[3]);
            xl[(e4 + 0) * 128 + (mm ^ (((e4 + 0) >> 2) & 31))] = v.x;
            xl[(e4 + 1) * 128 + (mm ^ (((e4 + 1) >> 2) & 31))] = v.y;
            xl[(e4 + 2) * 128 + (mm ^ (((e4 + 2) >> 2) & 31))] = v.z;
            xl[(e4 + 3) * 128 + (mm ^ (((e4 + 3) >> 2) & 31))] = v.w;
        }
    }
    __syncthreads();
    const int k    = t & 63;
    const int osub = t >> 6;             // 0..7
    const int o0   = ob4 * 16 + osub * 2;
    float pr0[2] = {0.f, 0.f}, pi0[2] = {0.f, 0.f};
    float pr1[2] = {0.f, 0.f}, pi1[2] = {0.f, 0.f};
    const unsigned int* wp = Wp + (size_t)o0 * 64 + k;
    #pragma unroll 4
    for (int e = 0; e < E_DIM; ++e) {
        const unsigned int w0 = wp[e * 4096];
        const unsigned int w1 = wp[e * 4096 + 64];
        const float a0 = __uint_as_float(w0 << 16);
        const float b0 = __uint_as_float(w0 & 0xFFFF0000u);
        const float a1 = __uint_as_float(w1 << 16);
        const float b1 = __uint_as_float(w1 & 0xFFFF0000u);
        const int swz = (e >> 2) & 31;
        #pragma unroll
        for (int b = 0; b < 2; ++b) {
            const float Xr = xf[b * 8192 + e * 128 + (k ^ swz)];
            const float Xi = xf[b * 8192 + e * 128 + 64 + (k ^ swz)];
            pr0[b] = fmaf(Xr, a0, fmaf(-Xi, b0, pr0[b]));
            pi0[b] = fmaf(Xr, b0, fmaf( Xi, a0, pi0[b]));
            pr1[b] = fmaf(Xr, a1, fmaf(-Xi, b1, pr1[b]));
            pi1[b] = fmaf(Xr, b1, fmaf( Xi, a1, pi1[b]));
        }
    }
    const float sc = (idx[k] == 0 ? 1.0f : 2.0f) / (float)S_LEN;
    const int kp = k >> 3, kl = k & 7;
    const int P0 = posP(o0), P1 = posP(o0 + 1);
    #pragma unroll
    for (int b = 0; b < 2; ++b) {
        unsigned short* qb = Qpk + (size_t)(2 * bhp + b) * 8192;
        qb[(kp * 64 + P0) * 8 + kl]       = f2bf(sc * pr0[b]);
        qb[(kp * 64 + P1) * 8 + kl]       = f2bf(sc * pr1[b]);
        qb[((8 + kp) * 64 + P0) * 8 + kl] = f2bf(-sc * pi0[b]);
        qb[((8 + kp) * 64 + P1) * 8 + kl] = f2bf(-sc * pi1[b]);
    }
}

// ---------------------------------------------------------------------------
// K2 (MFMA, LDS-free): out[128s x 64e] = U[128 x 128] * Q[128 x 64].
// grid = 128 bh x 32 s-chunks, 256 threads.  float4 NT stores.
// Ui in fragment order -> A loads are coalesced 1KB wave loads.  UNCHANGED.
// ---------------------------------------------------------------------------
__global__ __launch_bounds__(256) void k_inv(const unsigned short* __restrict__ Qpk,
                                             const unsigned short* __restrict__ Ui,
                                             float* __restrict__ out) {
    const int g  = blockIdx.x;                       // (bh%8) + sc*8 + (bh/8)*256
    const int bh = (g & 7) | ((g >> 8) << 3);
    const int sc = (g >> 3) & 31;
    const int t  = threadIdx.x;
    const int w  = t >> 6;
    const int l  = t & 63;
    const int lr = l & 15;
    const int lg = l >> 4;

    const unsigned short* qb = Qpk + (size_t)bh * 8192;
    // fragment-order A base: s-tiles su0 = sc*8 + w*2 (+1 for upper 16 rows)
    const unsigned short* U0 = Ui + (size_t)(sc * 8 + w * 2) * 2048 + l * 8;

    f32x4 acc[2][4];
    #pragma unroll
    for (int a = 0; a < 2; ++a)
        #pragma unroll
        for (int b = 0; b < 4; ++b) { acc[a][b][0]=0.f; acc[a][b][1]=0.f; acc[a][b][2]=0.f; acc[a][b][3]=0.f; }

    #pragma unroll
    for (int ksb = 0; ksb < 4; ++ksb) {
        const bf16x8 af0 = *(const bf16x8*)&U0[ksb * 512];
        const bf16x8 af1 = *(const bf16x8*)&U0[2048 + ksb * 512];
        #pragma unroll
        for (int nt = 0; nt < 4; ++nt) {
            const bf16x8 bfr = *(const bf16x8*)&qb[((ksb * 4 + lg) * 64 + nt * 16 + lr) * 8];
            acc[0][nt] = __builtin_amdgcn_mfma_f32_16x16x32_bf16(af0, bfr, acc[0][nt], 0, 0, 0);
            acc[1][nt] = __builtin_amdgcn_mfma_f32_16x16x32_bf16(af1, bfr, acc[1][nt], 0, 0, 0);
        }
    }
    float* ob = out + ((size_t)bh * S_LEN + sc * 128) * E_DIM;
    #pragma unroll
    for (int mt = 0; mt < 2; ++mt)
        #pragma unroll
        for (int r = 0; r < 4; ++r) {
            f32x4 v;
            v[0] = acc[mt][0][r]; v[1] = acc[mt][1][r];
            v[2] = acc[mt][2][r]; v[3] = acc[mt][3][r];
            __builtin_nontemporal_store(v,
                (f32x4*)&ob[(size_t)(w * 32 + mt * 16 + lg * 4 + r) * E_DIM + 4 * lr]);
        }
}

// ---------------------------------------------------------------------------
extern "C" void kernel_launch(void* const* d_in, const int* in_sizes, int n_in,
                              void* d_out, int out_size, void* d_ws, size_t ws_size,
                              hipStream_t stream) {
    const float* x  = (const float*)d_in[0];
    const float* wr = (const float*)d_in[1];
    const float* wi = (const float*)d_in[2];
    const int*  idx = (const int*)d_in[3];
    float* outp = (float*)d_out;
    char*  ws   = (char*)d_ws;

    // workspace (bytes): Tf 1MB | Ui 1MB | xfp 8MB (fp16) | Qpk 2MB | Wp 1MB
    unsigned short* Tf  = (unsigned short*)(ws);
    unsigned short* Ui  = (unsigned short*)(ws + (1u << 20));
    _Float16*       xfp = (_Float16*)(ws + (2u << 20));
    unsigned short* Qpk = (unsigned short*)(ws + (10u << 20));
    unsigned int*   Wp  = (unsigned int*)(ws + (12u << 20));

    hipLaunchKernelGGL(k_twp, dim3(2048), dim3(256), 0, stream,
                       idx, wr, wi, Tf, Ui, Wp);
    hipLaunchKernelGGL(k_fwd, dim3(BH * NCH), dim3(512), 0, stream,
                       x, Tf, xfp);
    hipLaunchKernelGGL(k_mix, dim3(256), dim3(512), 0, stream,
                       xfp, Wp, idx, Qpk);
    hipLaunchKernelGGL(k_inv, dim3(BH * 32), dim3(256), 0, stream,
                       Qpk, Ui, outp);
}

// Round 8
// 69.582 us; speedup vs baseline: 1.1175x; 1.0312x over previous
//
#include <hip/hip_runtime.h>

#define S_LEN 4096
#define E_DIM 64
#define MODES 64
#define BH    128
#define NCH   4
#define CH    1024      // S_LEN / NCH
#define BK    64        // K-step (s) per round in k_fwd

typedef __attribute__((ext_vector_type(8))) short bf16x8;   // 8 bf16 in 4 VGPRs
typedef __attribute__((ext_vector_type(4))) float f32x4;
typedef __attribute__((ext_vector_type(4))) _Float16 f16x4;

__device__ inline unsigned short f2bf(float f) {            // RTNE fp32->bf16
    unsigned int u = __float_as_uint(f);
    unsigned int r = u + 0x7FFFu + ((u >> 16) & 1u);
    return (unsigned short)(r >> 16);
}

// pack-position permutation (B-operand of both MFMA kernels): channel c ->
// position (c&3)*16 + (c>>2), so MFMA lane lr in n-tile nt owns channel
// 4*lr+nt, making the epilogue float4-contiguous per lane.
__device__ inline int posP(int c) { return ((c & 3) << 4) | (c >> 2); }

// ---------------------------------------------------------------------------
// Fused table build (one launch).  Twiddle tables in MFMA-FRAGMENT order
// (16-row x 32-col bf16 tiles, lane-major), so every A-operand load in
// k_fwd/k_inv is a single coalesced 1KB wave load instead of a 16-row gather.
// __sincosf (R6, proven bf16-bit-identical) — angles in [0,2pi).
// NEW (R8): weight prepack in o-PAIRED layout Wq[o>>1][e][k][2] so k_mix
// fetches both o0/o0+1 weights with ONE aligned uint2 load (wave-contiguous).
// ---------------------------------------------------------------------------
__global__ __launch_bounds__(256) void k_twp(const int* __restrict__ idx,
                                             const float* __restrict__ wr,
                                             const float* __restrict__ wi,
                                             unsigned short* __restrict__ Tf,
                                             unsigned short* __restrict__ Ui,
                                             unsigned int* __restrict__ Wq) {
    if (blockIdx.x < 1024) {
        int id = blockIdx.x * 256 + threadIdx.x;   // 64*4096
        int j = id >> 12;                          // mode row 0..63
        int s = id & (S_LEN - 1);
        int m = (idx[j] * s) & (S_LEN - 1);
        float ang = (float)m * (6.283185307179586476925287f / (float)S_LEN);
        float sv, cv;
        __sincosf(ang, &sv, &cv);
        // Tf fragment layout: mrow=j -> cos, mrow=64+j -> -sin
        const int tb = (s >> 5) * 4096 + ((s >> 3) & 3) * 128 + (s & 7);
        Tf[tb + ((j >> 4) * 64 + (j & 15)) * 8]              = f2bf(cv);
        Tf[tb + ((4 + (j >> 4)) * 64 + (j & 15)) * 8]        = f2bf(-sv);
        // Ui fragment layout: q=j -> cos, q=64+j -> +sin
        const int ub = (s >> 4) * 2048 + (s & 15) * 8;
        const int qc = ((j >> 3) & 3) * 128 + (j & 7);
        Ui[ub + (j >> 5) * 512 + qc]                          = f2bf(cv);
        Ui[ub + (2 + (j >> 5)) * 512 + qc]                    = f2bf(sv);
    } else {
        const int i = (blockIdx.x - 1024) * 256 + threadIdx.x;   // 262144
        // src linear i = e*4096 + o*64 + k  (wr/wi are [E][E][MODES])
        const int k = i & 63;
        const int o = (i >> 6) & 63;
        const int e = i >> 12;
        const unsigned int pk = (unsigned int)f2bf(wr[i]) | ((unsigned int)f2bf(wi[i]) << 16);
        Wq[(size_t)(o >> 1) * 8192 + e * 128 + k * 2 + (o & 1)] = pk;
    }
}

// ---------------------------------------------------------------------------
// K1 (MFMA): partial C[128m][64e] = T[128 x 1024chunk] * x[1024 x 64] per bh.
// grid = 128 bh x 4 chunks = 512 blocks (2/CU), 512 threads (8 waves).
// R4 structure (proven): double-buffered Xs, one barrier per K-step; iter ks
// packs data for ks+1 and issues NT loads for ks+2.
// fp16 xfp partials (R7, proven).  UNCHANGED.
// ---------------------------------------------------------------------------
__global__ __launch_bounds__(512) void k_fwd(const float* __restrict__ x,
                                             const unsigned short* __restrict__ Tf,
                                             _Float16* __restrict__ xfp) {
    __shared__ unsigned short Xs[2][8 * 64 * 8];   // 2 x 8 KB, packs [kp][pos][8k]
    const int bh = blockIdx.x >> 2;
    const int c  = blockIdx.x & 3;
    const int t  = threadIdx.x;
    const int w  = t >> 6;          // wave 0..7
    const int l  = t & 63;
    const int lr = l & 15;
    const int lg = l >> 4;
    const int NIT = CH / BK;        // 16

    f32x4 acc[4];
    #pragma unroll
    for (int i = 0; i < 4; ++i) { acc[i][0]=0.f; acc[i][1]=0.f; acc[i][2]=0.f; acc[i][3]=0.f; }

    const float* xb = x + ((size_t)bh * S_LEN + c * CH) * E_DIM;
    // fragment-order A base: tile (st = c*32 + ks*2 + ksub, w), lane l
    const unsigned short* Tw = Tf + (size_t)(c * 32) * 4096 + w * 512 + l * 8;
    const int pkoff = (w * 64 + posP(l)) * 8;

    float xe[8];
    {   // iter-0 data, pack into Xs[0]
        const float* xg = xb + (size_t)(w * 8) * E_DIM + l;
        #pragma unroll
        for (int j = 0; j < 8; ++j) xe[j] = __builtin_nontemporal_load(xg + (size_t)j * E_DIM);
        union { unsigned short u[8]; bf16x8 v; } pk;
        #pragma unroll
        for (int j = 0; j < 8; ++j) pk.u[j] = f2bf(xe[j]);
        *(bf16x8*)&Xs[0][pkoff] = pk.v;
    }
    {   // issue loads for iter 1
        const float* xg = xb + (size_t)(BK + w * 8) * E_DIM + l;
        #pragma unroll
        for (int j = 0; j < 8; ++j) xe[j] = __builtin_nontemporal_load(xg + (size_t)j * E_DIM);
    }
    __syncthreads();

    #pragma unroll 2
    for (int ks = 0; ks < NIT; ++ks) {
        const int p = ks & 1;
        if (ks + 1 < NIT) {
            // pack xe (data for iter ks+1) into the other buffer
            union { unsigned short u[8]; bf16x8 v; } pk;
            #pragma unroll
            for (int j = 0; j < 8; ++j) pk.u[j] = f2bf(xe[j]);
            *(bf16x8*)&Xs[p ^ 1][pkoff] = pk.v;
            if (ks + 2 < NIT) {
                const float* xg = xb + (size_t)((ks + 2) * BK + w * 8) * E_DIM + l;
                #pragma unroll
                for (int j = 0; j < 8; ++j) xe[j] = __builtin_nontemporal_load(xg + (size_t)j * E_DIM);
            }
        }
        #pragma unroll
        for (int ksub = 0; ksub < 2; ++ksub) {
            const bf16x8 af = *(const bf16x8*)&Tw[(size_t)(ks * 2 + ksub) * 4096];
            #pragma unroll
            for (int nt = 0; nt < 4; ++nt) {
                const bf16x8 bfr = *(const bf16x8*)&Xs[p][((ksub * 4 + lg) * 64 + nt * 16 + lr) * 8];
                acc[nt] = __builtin_amdgcn_mfma_f32_16x16x32_bf16(af, bfr, acc[nt], 0, 0, 0);
            }
        }
        __syncthreads();
    }
    // posP-permuted packs: lane lr's tile nt holds e = 4*lr + nt -> f16x4 rows
    _Float16* ob = xfp + ((size_t)c * BH + bh) * 8192;
    #pragma unroll
    for (int r = 0; r < 4; ++r) {
        f16x4 v;
        v[0] = (_Float16)acc[0][r]; v[1] = (_Float16)acc[1][r];
        v[2] = (_Float16)acc[2][r]; v[3] = (_Float16)acc[3][r];
        *(f16x4*)&ob[(size_t)(16 * w + lg * 4 + r) * 64 + 4 * lr] = v;
    }
}

// ---------------------------------------------------------------------------
// M (fp32 accum, bf16 packed weights): fused 4-plane chunk reduction + apply
// complex weights, scale, fold signs; write bf16 B-packs Qpk[bh][kp][pos][8k].
// R3-proven shape: 256 blocks x 512 threads, block = 2 bh x 16 o, 64KB LDS.
// NEW (R8): o-paired Wq layout -> one uint2 load per e (was 2 x 4B at 16KB
// stride); e-loop unroll 8 for deeper load pipelining (k_mix is Wp-latency
// bound per R6's +3.6us at doubled load count).
// ---------------------------------------------------------------------------
__global__ __launch_bounds__(512) void k_mix(const _Float16* __restrict__ xfp,
                                             const unsigned int* __restrict__ Wq,
                                             const int* __restrict__ idx,
                                             unsigned short* __restrict__ Qpk) {
    __shared__ float xf[2 * 64 * 128];   // [b][e][m^swz], 64 KB
    const int g   = blockIdx.x;
    const int bhp = g & 63;              // bh pair: 2*bhp, 2*bhp+1
    const int ob4 = g >> 6;              // 16-o group 0..3
    const int t   = threadIdx.x;
    const size_t P = (size_t)BH * 8192;  // chunk plane stride (halves)
    #pragma unroll
    for (int b = 0; b < 2; ++b) {
        const _Float16* x0 = xfp + (size_t)(2 * bhp + b) * 8192;
        float* xl = xf + b * 8192;
        #pragma unroll
        for (int i = 0; i < 4; ++i) {
            const int off = i * 2048 + t * 4;
            const int mm  = off >> 6;
            const int e4  = off & 63;
            f16x4 v0 = *(const f16x4*)(x0 + off);
            f16x4 v1 = *(const f16x4*)(x0 + P + off);
            f16x4 v2 = *(const f16x4*)(x0 + 2 * P + off);
            f16x4 v3 = *(const f16x4*)(x0 + 3 * P + off);
            float4 v;
            v.x = ((float)v0[0] + (float)v1[0]) + ((float)v2[0] + (float)v3[0]);
            v.y = ((float)v0[1] + (float)v1[1]) + ((float)v2[1] + (float)v3[1]);
            v.z = ((float)v0[2] + (float)v1[2]) + ((float)v2[2] + (float)v3[2]);
            v.w = ((float)v0[3] + (float)v1[3]) + ((float)v2[3] + (float)v3[3]);
            xl[(e4 + 0) * 128 + (mm ^ (((e4 + 0) >> 2) & 31))] = v.x;
            xl[(e4 + 1) * 128 + (mm ^ (((e4 + 1) >> 2) & 31))] = v.y;
            xl[(e4 + 2) * 128 + (mm ^ (((e4 + 2) >> 2) & 31))] = v.z;
            xl[(e4 + 3) * 128 + (mm ^ (((e4 + 3) >> 2) & 31))] = v.w;
        }
    }
    __syncthreads();
    const int k    = t & 63;
    const int osub = t >> 6;             // 0..7
    const int o0   = ob4 * 16 + osub * 2;
    float pr0[2] = {0.f, 0.f}, pi0[2] = {0.f, 0.f};
    float pr1[2] = {0.f, 0.f}, pi1[2] = {0.f, 0.f};
    // o-paired layout: Wq[(o0>>1)][e][k][2] -> one uint2 per e
    const unsigned int* wq = Wq + (size_t)(o0 >> 1) * 8192 + k * 2;
    #pragma unroll 8
    for (int e = 0; e < E_DIM; ++e) {
        const uint2 wv = *(const uint2*)&wq[e * 128];
        const unsigned int w0 = wv.x;
        const unsigned int w1 = wv.y;
        const float a0 = __uint_as_float(w0 << 16);
        const float b0 = __uint_as_float(w0 & 0xFFFF0000u);
        const float a1 = __uint_as_float(w1 << 16);
        const float b1 = __uint_as_float(w1 & 0xFFFF0000u);
        const int swz = (e >> 2) & 31;
        #pragma unroll
        for (int b = 0; b < 2; ++b) {
            const float Xr = xf[b * 8192 + e * 128 + (k ^ swz)];
            const float Xi = xf[b * 8192 + e * 128 + 64 + (k ^ swz)];
            pr0[b] = fmaf(Xr, a0, fmaf(-Xi, b0, pr0[b]));
            pi0[b] = fmaf(Xr, b0, fmaf( Xi, a0, pi0[b]));
            pr1[b] = fmaf(Xr, a1, fmaf(-Xi, b1, pr1[b]));
            pi1[b] = fmaf(Xr, b1, fmaf( Xi, a1, pi1[b]));
        }
    }
    const float sc = (idx[k] == 0 ? 1.0f : 2.0f) / (float)S_LEN;
    const int kp = k >> 3, kl = k & 7;
    const int P0 = posP(o0), P1 = posP(o0 + 1);
    #pragma unroll
    for (int b = 0; b < 2; ++b) {
        unsigned short* qb = Qpk + (size_t)(2 * bhp + b) * 8192;
        qb[(kp * 64 + P0) * 8 + kl]       = f2bf(sc * pr0[b]);
        qb[(kp * 64 + P1) * 8 + kl]       = f2bf(sc * pr1[b]);
        qb[((8 + kp) * 64 + P0) * 8 + kl] = f2bf(-sc * pi0[b]);
        qb[((8 + kp) * 64 + P1) * 8 + kl] = f2bf(-sc * pi1[b]);
    }
}

// ---------------------------------------------------------------------------
// K2 (MFMA, LDS-free): out[128s x 64e] = U[128 x 128] * Q[128 x 64].
// grid = 128 bh x 32 s-chunks, 256 threads.  float4 NT stores.
// Ui in fragment order -> A loads are coalesced 1KB wave loads.  UNCHANGED.
// ---------------------------------------------------------------------------
__global__ __launch_bounds__(256) void k_inv(const unsigned short* __restrict__ Qpk,
                                             const unsigned short* __restrict__ Ui,
                                             float* __restrict__ out) {
    const int g  = blockIdx.x;                       // (bh%8) + sc*8 + (bh/8)*256
    const int bh = (g & 7) | ((g >> 8) << 3);
    const int sc = (g >> 3) & 31;
    const int t  = threadIdx.x;
    const int w  = t >> 6;
    const int l  = t & 63;
    const int lr = l & 15;
    const int lg = l >> 4;

    const unsigned short* qb = Qpk + (size_t)bh * 8192;
    // fragment-order A base: s-tiles su0 = sc*8 + w*2 (+1 for upper 16 rows)
    const unsigned short* U0 = Ui + (size_t)(sc * 8 + w * 2) * 2048 + l * 8;

    f32x4 acc[2][4];
    #pragma unroll
    for (int a = 0; a < 2; ++a)
        #pragma unroll
        for (int b = 0; b < 4; ++b) { acc[a][b][0]=0.f; acc[a][b][1]=0.f; acc[a][b][2]=0.f; acc[a][b][3]=0.f; }

    #pragma unroll
    for (int ksb = 0; ksb < 4; ++ksb) {
        const bf16x8 af0 = *(const bf16x8*)&U0[ksb * 512];
        const bf16x8 af1 = *(const bf16x8*)&U0[2048 + ksb * 512];
        #pragma unroll
        for (int nt = 0; nt < 4; ++nt) {
            const bf16x8 bfr = *(const bf16x8*)&qb[((ksb * 4 + lg) * 64 + nt * 16 + lr) * 8];
            acc[0][nt] = __builtin_amdgcn_mfma_f32_16x16x32_bf16(af0, bfr, acc[0][nt], 0, 0, 0);
            acc[1][nt] = __builtin_amdgcn_mfma_f32_16x16x32_bf16(af1, bfr, acc[1][nt], 0, 0, 0);
        }
    }
    float* ob = out + ((size_t)bh * S_LEN + sc * 128) * E_DIM;
    #pragma unroll
    for (int mt = 0; mt < 2; ++mt)
        #pragma unroll
        for (int r = 0; r < 4; ++r) {
            f32x4 v;
            v[0] = acc[mt][0][r]; v[1] = acc[mt][1][r];
            v[2] = acc[mt][2][r]; v[3] = acc[mt][3][r];
            __builtin_nontemporal_store(v,
                (f32x4*)&ob[(size_t)(w * 32 + mt * 16 + lg * 4 + r) * E_DIM + 4 * lr]);
        }
}

// ---------------------------------------------------------------------------
extern "C" void kernel_launch(void* const* d_in, const int* in_sizes, int n_in,
                              void* d_out, int out_size, void* d_ws, size_t ws_size,
                              hipStream_t stream) {
    const float* x  = (const float*)d_in[0];
    const float* wr = (const float*)d_in[1];
    const float* wi = (const float*)d_in[2];
    const int*  idx = (const int*)d_in[3];
    float* outp = (float*)d_out;
    char*  ws   = (char*)d_ws;

    // workspace (bytes): Tf 1MB | Ui 1MB | xfp 8MB (fp16) | Qpk 2MB | Wq 1MB
    unsigned short* Tf  = (unsigned short*)(ws);
    unsigned short* Ui  = (unsigned short*)(ws + (1u << 20));
    _Float16*       xfp = (_Float16*)(ws + (2u << 20));
    unsigned short* Qpk = (unsigned short*)(ws + (10u << 20));
    unsigned int*   Wq  = (unsigned int*)(ws + (12u << 20));

    hipLaunchKernelGGL(k_twp, dim3(2048), dim3(256), 0, stream,
                       idx, wr, wi, Tf, Ui, Wq);
    hipLaunchKernelGGL(k_fwd, dim3(BH * NCH), dim3(512), 0, stream,
                       x, Tf, xfp);
    hipLaunchKernelGGL(k_mix, dim3(256), dim3(512), 0, stream,
                       xfp, Wq, idx, Qpk);
    hipLaunchKernelGGL(k_inv, dim3(BH * 32), dim3(256), 0, stream,
                       Qpk, Ui, outp);
}

// Round 9
// 69.576 us; speedup vs baseline: 1.1176x; 1.0001x over previous
//
#include <hip/hip_runtime.h>

#define S_LEN 4096
#define E_DIM 64
#define MODES 64
#define BH    128
#define NCH   4
#define CH    1024      // S_LEN / NCH
#define BK    64        // K-step (s) per round in k_fwd

typedef __attribute__((ext_vector_type(8))) short bf16x8;   // 8 bf16 in 4 VGPRs
typedef __attribute__((ext_vector_type(4))) float f32x4;
typedef __attribute__((ext_vector_type(4))) _Float16 f16x4;

__device__ inline unsigned short f2bf(float f) {            // RTNE fp32->bf16
    unsigned int u = __float_as_uint(f);
    unsigned int r = u + 0x7FFFu + ((u >> 16) & 1u);
    return (unsigned short)(r >> 16);
}

// pack-position permutation (B-operand of both MFMA kernels): channel c ->
// position (c&3)*16 + (c>>2), so MFMA lane lr in n-tile nt owns channel
// 4*lr+nt, making the epilogue float4-contiguous per lane.
__device__ inline int posP(int c) { return ((c & 3) << 4) | (c >> 2); }

// ---------------------------------------------------------------------------
// Fused table build (one launch).  Twiddle tables in MFMA-FRAGMENT order
// (16-row x 32-col bf16 tiles, lane-major), so every A-operand load in
// k_fwd/k_inv is a single coalesced 1KB wave load instead of a 16-row gather.
// __sincosf (R6, proven bf16-bit-identical) — angles in [0,2pi).
// Weight prepack in o-PAIRED layout Wq[o>>1][e][k][2] (R8, proven).
// ---------------------------------------------------------------------------
__global__ __launch_bounds__(256) void k_twp(const int* __restrict__ idx,
                                             const float* __restrict__ wr,
                                             const float* __restrict__ wi,
                                             unsigned short* __restrict__ Tf,
                                             unsigned short* __restrict__ Ui,
                                             unsigned int* __restrict__ Wq) {
    if (blockIdx.x < 1024) {
        int id = blockIdx.x * 256 + threadIdx.x;   // 64*4096
        int j = id >> 12;                          // mode row 0..63
        int s = id & (S_LEN - 1);
        int m = (idx[j] * s) & (S_LEN - 1);
        float ang = (float)m * (6.283185307179586476925287f / (float)S_LEN);
        float sv, cv;
        __sincosf(ang, &sv, &cv);
        // Tf fragment layout: mrow=j -> cos, mrow=64+j -> -sin
        const int tb = (s >> 5) * 4096 + ((s >> 3) & 3) * 128 + (s & 7);
        Tf[tb + ((j >> 4) * 64 + (j & 15)) * 8]              = f2bf(cv);
        Tf[tb + ((4 + (j >> 4)) * 64 + (j & 15)) * 8]        = f2bf(-sv);
        // Ui fragment layout: q=j -> cos, q=64+j -> +sin
        const int ub = (s >> 4) * 2048 + (s & 15) * 8;
        const int qc = ((j >> 3) & 3) * 128 + (j & 7);
        Ui[ub + (j >> 5) * 512 + qc]                          = f2bf(cv);
        Ui[ub + (2 + (j >> 5)) * 512 + qc]                    = f2bf(sv);
    } else {
        const int i = (blockIdx.x - 1024) * 256 + threadIdx.x;   // 262144
        // src linear i = e*4096 + o*64 + k  (wr/wi are [E][E][MODES])
        const int k = i & 63;
        const int o = (i >> 6) & 63;
        const int e = i >> 12;
        const unsigned int pk = (unsigned int)f2bf(wr[i]) | ((unsigned int)f2bf(wi[i]) << 16);
        Wq[(size_t)(o >> 1) * 8192 + e * 128 + k * 2 + (o & 1)] = pk;
    }
}

// ---------------------------------------------------------------------------
// K1 (MFMA): partial C[128m][64e] = T[128 x 1024chunk] * x[1024 x 64] per bh.
// grid = 128 bh x 4 chunks = 512 blocks (2/CU), 512 threads (8 waves).
// R4 pipeline (proven): double-buffered Xs, one barrier per K-step; iter ks
// packs data for ks+1 and issues NT loads for ks+2.
// NEW (R9): x loads widened to float4 (16 B/lane, 1 KB/wave, 2 loads/thread
// per K-step instead of 8 scalar dwords) — lane l reads row w*8+j*4+(l>>4),
// cols 4*(l&15)..+3; 4 consecutive rows per load = perfectly coalesced.
// LDS pack becomes 8 scalar b16 scatter-writes (posP-consistent), absorbed
// by the DS pipe.  Values and Xs layout bit-identical to R8.
// ---------------------------------------------------------------------------
__global__ __launch_bounds__(512) void k_fwd(const float* __restrict__ x,
                                             const unsigned short* __restrict__ Tf,
                                             _Float16* __restrict__ xfp) {
    __shared__ unsigned short Xs[2][8 * 64 * 8];   // 2 x 8 KB, packs [kp][pos][8k]
    const int bh = blockIdx.x >> 2;
    const int c  = blockIdx.x & 3;
    const int t  = threadIdx.x;
    const int w  = t >> 6;          // wave 0..7
    const int l  = t & 63;
    const int lr = l & 15;
    const int lg = l >> 4;
    const int q  = l & 15;          // e-quad index (cols 4q..4q+3)
    const int h  = l >> 4;          // row-sub within a float4 load (0..3)
    const int NIT = CH / BK;        // 16

    f32x4 acc[4];
    #pragma unroll
    for (int i = 0; i < 4; ++i) { acc[i][0]=0.f; acc[i][1]=0.f; acc[i][2]=0.f; acc[i][3]=0.f; }

    const float* xb = x + ((size_t)bh * S_LEN + c * CH) * E_DIM;
    // fragment-order A base: tile (st = c*32 + ks*2 + ksub, w), lane l
    const unsigned short* Tw = Tf + (size_t)(c * 32) * 4096 + w * 512 + l * 8;
    // float4 load base: rows w*8 + j*4 + h, cols 4q..4q+3  (j in {0,1})
    const float* xg0 = xb + (size_t)(w * 8 + h) * E_DIM + 4 * q;
    // LDS scatter for elem (j,i): chan e=4q+i -> pos 16i+q, klane j*4+h
    const int so = w * 512 + q * 8 + h;   // + i*128 + j*4

    f32x4 xv[2];
    {   // iter-0 data: load + pack into Xs[0]
        f32x4 a0 = __builtin_nontemporal_load((const f32x4*)xg0);
        f32x4 a1 = __builtin_nontemporal_load((const f32x4*)(xg0 + 256));
        #pragma unroll
        for (int i = 0; i < 4; ++i) {
            Xs[0][so + i * 128 + 0] = f2bf(a0[i]);
            Xs[0][so + i * 128 + 4] = f2bf(a1[i]);
        }
        // issue loads for iter 1
        xv[0] = __builtin_nontemporal_load((const f32x4*)(xg0 + 4096));
        xv[1] = __builtin_nontemporal_load((const f32x4*)(xg0 + 4096 + 256));
    }
    __syncthreads();

    #pragma unroll 2
    for (int ks = 0; ks < NIT; ++ks) {
        const int p = ks & 1;
        if (ks + 1 < NIT) {
            // pack xv (data for iter ks+1) into the other buffer
            #pragma unroll
            for (int i = 0; i < 4; ++i) {
                Xs[p ^ 1][so + i * 128 + 0] = f2bf(xv[0][i]);
                Xs[p ^ 1][so + i * 128 + 4] = f2bf(xv[1][i]);
            }
            if (ks + 2 < NIT) {
                const float* xg = xg0 + (size_t)(ks + 2) * 4096;
                xv[0] = __builtin_nontemporal_load((const f32x4*)xg);
                xv[1] = __builtin_nontemporal_load((const f32x4*)(xg + 256));
            }
        }
        #pragma unroll
        for (int ksub = 0; ksub < 2; ++ksub) {
            const bf16x8 af = *(const bf16x8*)&Tw[(size_t)(ks * 2 + ksub) * 4096];
            #pragma unroll
            for (int nt = 0; nt < 4; ++nt) {
                const bf16x8 bfr = *(const bf16x8*)&Xs[p][((ksub * 4 + lg) * 64 + nt * 16 + lr) * 8];
                acc[nt] = __builtin_amdgcn_mfma_f32_16x16x32_bf16(af, bfr, acc[nt], 0, 0, 0);
            }
        }
        __syncthreads();
    }
    // posP-permuted packs: lane lr's tile nt holds e = 4*lr + nt -> f16x4 rows
    _Float16* ob = xfp + ((size_t)c * BH + bh) * 8192;
    #pragma unroll
    for (int r = 0; r < 4; ++r) {
        f16x4 v;
        v[0] = (_Float16)acc[0][r]; v[1] = (_Float16)acc[1][r];
        v[2] = (_Float16)acc[2][r]; v[3] = (_Float16)acc[3][r];
        *(f16x4*)&ob[(size_t)(16 * w + lg * 4 + r) * 64 + 4 * lr] = v;
    }
}

// ---------------------------------------------------------------------------
// M (fp32 accum, bf16 packed weights): fused 4-plane chunk reduction + apply
// complex weights, scale, fold signs; write bf16 B-packs Qpk[bh][kp][pos][8k].
// R3-proven shape + R8 o-paired Wq (one uint2/e) + unroll 8.  UNCHANGED.
// ---------------------------------------------------------------------------
__global__ __launch_bounds__(512) void k_mix(const _Float16* __restrict__ xfp,
                                             const unsigned int* __restrict__ Wq,
                                             const int* __restrict__ idx,
                                             unsigned short* __restrict__ Qpk) {
    __shared__ float xf[2 * 64 * 128];   // [b][e][m^swz], 64 KB
    const int g   = blockIdx.x;
    const int bhp = g & 63;              // bh pair: 2*bhp, 2*bhp+1
    const int ob4 = g >> 6;              // 16-o group 0..3
    const int t   = threadIdx.x;
    const size_t P = (size_t)BH * 8192;  // chunk plane stride (halves)
    #pragma unroll
    for (int b = 0; b < 2; ++b) {
        const _Float16* x0 = xfp + (size_t)(2 * bhp + b) * 8192;
        float* xl = xf + b * 8192;
        #pragma unroll
        for (int i = 0; i < 4; ++i) {
            const int off = i * 2048 + t * 4;
            const int mm  = off >> 6;
            const int e4  = off & 63;
            f16x4 v0 = *(const f16x4*)(x0 + off);
            f16x4 v1 = *(const f16x4*)(x0 + P + off);
            f16x4 v2 = *(const f16x4*)(x0 + 2 * P + off);
            f16x4 v3 = *(const f16x4*)(x0 + 3 * P + off);
            float4 v;
            v.x = ((float)v0[0] + (float)v1[0]) + ((float)v2[0] + (float)v3[0]);
            v.y = ((float)v0[1] + (float)v1[1]) + ((float)v2[1] + (float)v3[1]);
            v.z = ((float)v0[2] + (float)v1[2]) + ((float)v2[2] + (float)v3[2]);
            v.w = ((float)v0[3] + (float)v1[3]) + ((float)v2[3] + (float)v3[3]);
            xl[(e4 + 0) * 128 + (mm ^ (((e4 + 0) >> 2) & 31))] = v.x;
            xl[(e4 + 1) * 128 + (mm ^ (((e4 + 1) >> 2) & 31))] = v.y;
            xl[(e4 + 2) * 128 + (mm ^ (((e4 + 2) >> 2) & 31))] = v.z;
            xl[(e4 + 3) * 128 + (mm ^ (((e4 + 3) >> 2) & 31))] = v.w;
        }
    }
    __syncthreads();
    const int k    = t & 63;
    const int osub = t >> 6;             // 0..7
    const int o0   = ob4 * 16 + osub * 2;
    float pr0[2] = {0.f, 0.f}, pi0[2] = {0.f, 0.f};
    float pr1[2] = {0.f, 0.f}, pi1[2] = {0.f, 0.f};
    // o-paired layout: Wq[(o0>>1)][e][k][2] -> one uint2 per e
    const unsigned int* wq = Wq + (size_t)(o0 >> 1) * 8192 + k * 2;
    #pragma unroll 8
    for (int e = 0; e < E_DIM; ++e) {
        const uint2 wv = *(const uint2*)&wq[e * 128];
        const unsigned int w0 = wv.x;
        const unsigned int w1 = wv.y;
        const float a0 = __uint_as_float(w0 << 16);
        const float b0 = __uint_as_float(w0 & 0xFFFF0000u);
        const float a1 = __uint_as_float(w1 << 16);
        const float b1 = __uint_as_float(w1 & 0xFFFF0000u);
        const int swz = (e >> 2) & 31;
        #pragma unroll
        for (int b = 0; b < 2; ++b) {
            const float Xr = xf[b * 8192 + e * 128 + (k ^ swz)];
            const float Xi = xf[b * 8192 + e * 128 + 64 + (k ^ swz)];
            pr0[b] = fmaf(Xr, a0, fmaf(-Xi, b0, pr0[b]));
            pi0[b] = fmaf(Xr, b0, fmaf( Xi, a0, pi0[b]));
            pr1[b] = fmaf(Xr, a1, fmaf(-Xi, b1, pr1[b]));
            pi1[b] = fmaf(Xr, b1, fmaf( Xi, a1, pi1[b]));
        }
    }
    const float sc = (idx[k] == 0 ? 1.0f : 2.0f) / (float)S_LEN;
    const int kp = k >> 3, kl = k & 7;
    const int P0 = posP(o0), P1 = posP(o0 + 1);
    #pragma unroll
    for (int b = 0; b < 2; ++b) {
        unsigned short* qb = Qpk + (size_t)(2 * bhp + b) * 8192;
        qb[(kp * 64 + P0) * 8 + kl]       = f2bf(sc * pr0[b]);
        qb[(kp * 64 + P1) * 8 + kl]       = f2bf(sc * pr1[b]);
        qb[((8 + kp) * 64 + P0) * 8 + kl] = f2bf(-sc * pi0[b]);
        qb[((8 + kp) * 64 + P1) * 8 + kl] = f2bf(-sc * pi1[b]);
    }
}

// ---------------------------------------------------------------------------
// K2 (MFMA, LDS-free): out[128s x 64e] = U[128 x 128] * Q[128 x 64].
// grid = 128 bh x 32 s-chunks, 256 threads.  float4 NT stores.
// Ui in fragment order -> A loads are coalesced 1KB wave loads.  UNCHANGED.
// ---------------------------------------------------------------------------
__global__ __launch_bounds__(256) void k_inv(const unsigned short* __restrict__ Qpk,
                                             const unsigned short* __restrict__ Ui,
                                             float* __restrict__ out) {
    const int g  = blockIdx.x;                       // (bh%8) + sc*8 + (bh/8)*256
    const int bh = (g & 7) | ((g >> 8) << 3);
    const int sc = (g >> 3) & 31;
    const int t  = threadIdx.x;
    const int w  = t >> 6;
    const int l  = t & 63;
    const int lr = l & 15;
    const int lg = l >> 4;

    const unsigned short* qb = Qpk + (size_t)bh * 8192;
    // fragment-order A base: s-tiles su0 = sc*8 + w*2 (+1 for upper 16 rows)
    const unsigned short* U0 = Ui + (size_t)(sc * 8 + w * 2) * 2048 + l * 8;

    f32x4 acc[2][4];
    #pragma unroll
    for (int a = 0; a < 2; ++a)
        #pragma unroll
        for (int b = 0; b < 4; ++b) { acc[a][b][0]=0.f; acc[a][b][1]=0.f; acc[a][b][2]=0.f; acc[a][b][3]=0.f; }

    #pragma unroll
    for (int ksb = 0; ksb < 4; ++ksb) {
        const bf16x8 af0 = *(const bf16x8*)&U0[ksb * 512];
        const bf16x8 af1 = *(const bf16x8*)&U0[2048 + ksb * 512];
        #pragma unroll
        for (int nt = 0; nt < 4; ++nt) {
            const bf16x8 bfr = *(const bf16x8*)&qb[((ksb * 4 + lg) * 64 + nt * 16 + lr) * 8];
            acc[0][nt] = __builtin_amdgcn_mfma_f32_16x16x32_bf16(af0, bfr, acc[0][nt], 0, 0, 0);
            acc[1][nt] = __builtin_amdgcn_mfma_f32_16x16x32_bf16(af1, bfr, acc[1][nt], 0, 0, 0);
        }
    }
    float* ob = out + ((size_t)bh * S_LEN + sc * 128) * E_DIM;
    #pragma unroll
    for (int mt = 0; mt < 2; ++mt)
        #pragma unroll
        for (int r = 0; r < 4; ++r) {
            f32x4 v;
            v[0] = acc[mt][0][r]; v[1] = acc[mt][1][r];
            v[2] = acc[mt][2][r]; v[3] = acc[mt][3][r];
            __builtin_nontemporal_store(v,
                (f32x4*)&ob[(size_t)(w * 32 + mt * 16 + lg * 4 + r) * E_DIM + 4 * lr]);
        }
}

// ---------------------------------------------------------------------------
extern "C" void kernel_launch(void* const* d_in, const int* in_sizes, int n_in,
                              void* d_out, int out_size, void* d_ws, size_t ws_size,
                              hipStream_t stream) {
    const float* x  = (const float*)d_in[0];
    const float* wr = (const float*)d_in[1];
    const float* wi = (const float*)d_in[2];
    const int*  idx = (const int*)d_in[3];
    float* outp = (float*)d_out;
    char*  ws   = (char*)d_ws;

    // workspace (bytes): Tf 1MB | Ui 1MB | xfp 8MB (fp16) | Qpk 2MB | Wq 1MB
    unsigned short* Tf  = (unsigned short*)(ws);
    unsigned short* Ui  = (unsigned short*)(ws + (1u << 20));
    _Float16*       xfp = (_Float16*)(ws + (2u << 20));
    unsigned short* Qpk = (unsigned short*)(ws + (10u << 20));
    unsigned int*   Wq  = (unsigned int*)(ws + (12u << 20));

    hipLaunchKernelGGL(k_twp, dim3(2048), dim3(256), 0, stream,
                       idx, wr, wi, Tf, Ui, Wq);
    hipLaunchKernelGGL(k_fwd, dim3(BH * NCH), dim3(512), 0, stream,
                       x, Tf, xfp);
    hipLaunchKernelGGL(k_mix, dim3(256), dim3(512), 0, stream,
                       xfp, Wq, idx, Qpk);
    hipLaunchKernelGGL(k_inv, dim3(BH * 32), dim3(256), 0, stream,
                       Qpk, Ui, outp);
}